// Round 11
// baseline (42.188 us; speedup 1.0000x reference)
//
#include <hip/hip_runtime.h>

#define KN      1024
#define FAN_IN  16
#define NSP     64
#define MAPB    (NSP * NSP)
#define THRESH  12

__device__ __forceinline__ float tanh_fast(float x) {
    float ax = fabsf(x);
    float e  = __expf(-2.0f * ax);
    float r  = 1.0f - 2.0f * e * __builtin_amdgcn_rcpf(1.0f + e);
    return copysignf(r, x);
}

// Full-wave DPP shifts; bound_ctrl=1 zeroes shifted-in edge lane = conv zero-pad.
__device__ __forceinline__ float dpp_wshr1(float x) {  // lane L <- lane L-1
    return __int_as_float(__builtin_amdgcn_update_dpp(
        0, __float_as_int(x), 0x138, 0xF, 0xF, true));
}
__device__ __forceinline__ float dpp_wshl1(float x) {  // lane L <- lane L+1
    return __int_as_float(__builtin_amdgcn_update_dpp(
        0, __float_as_int(x), 0x130, 0xF, 0xF, true));
}

__device__ __forceinline__ unsigned short f2bf_rne(float x) {
    unsigned u = __float_as_uint(x);
    return (unsigned short)((u + 0x7FFFu + ((u >> 16) & 1u)) >> 16);
}
__device__ __forceinline__ float bf2f(unsigned short s) {
    return __uint_as_float(((unsigned)s) << 16);
}

// ---- pre-pass: f32 maps -> bf16 maps in d_ws (RNE). 4 floats/thread. ----
__global__ __launch_bounds__(256) void compress_kernel(
    const float* __restrict__ in, unsigned short* __restrict__ out16)
{
    const int i = (blockIdx.x * 256 + threadIdx.x) * 4;
    float4 v = *(const float4*)(in + i);
    ushort4 o;
    o.x = f2bf_rne(v.x); o.y = f2bf_rne(v.y);
    o.z = f2bf_rne(v.z); o.w = f2bf_rne(v.w);
    *(ushort4*)(out16 + i) = o;
}

// ---- main: R9-proven frame, bf16 payload. 1 block = 1 node, 512 threads. ----
// Wave wv owns rows 8wv..8wv+7; lane = column. Per channel: ONE global_load_lds
// issue stages the whole 8 KB bf16 map (double-buffered, 1 barrier/channel).
__global__ __launch_bounds__(512, 8) void decoder_bf16(
    const unsigned short* __restrict__ maps16,   // [1024][4096] bf16 (d_ws)
    const void*  __restrict__ prev_is_active,
    const int*   __restrict__ parent_indices,
    const float* __restrict__ Wt,
    const float* __restrict__ bias,
    float*       __restrict__ out)
{
    __shared__ unsigned short sbuf[2][MAPB];     // 2 x 8 KB

    const int k    = blockIdx.x;
    const int tid  = threadIdx.x;
    const int lane = tid & 63;
    const int wv   = tid >> 6;
    const int r0   = wv * 8;

    bool bytemode = false;
    {
        const unsigned* sv = (const unsigned*)prev_is_active;
        #pragma unroll
        for (int i = 0; i < 16; ++i)
            if (sv[i] > 1u) bytemode = true;
    }

    const int* pidx = parent_indices + k * FAN_IN;
    int cnt = 0;
    #pragma unroll
    for (int i = 0; i < FAN_IN; ++i) {
        int p = pidx[i];
        int f;
        if (bytemode) f = (((const unsigned char*)prev_is_active)[p] != 0);
        else          f = (((const int*)prev_is_active)[p] != 0);
        cnt += f;
    }
    const bool active = (cnt >= THRESH);

    const size_t obase = (size_t)k * MAPB;
    if (tid == 0)
        out[(size_t)KN * MAPB + k] = active ? 1.0f : 0.0f;

    if (!active) {
        float4 z = make_float4(0.f, 0.f, 0.f, 0.f);
        float4* o4 = (float4*)(out + obase);
        o4[tid]       = z;
        o4[tid + 512] = z;
        return;
    }

    const float mT = (wv > 0) ? 1.0f : 0.0f;
    const float mB = (wv < 7) ? 1.0f : 0.0f;
    const int   rT = (wv > 0) ? r0 - 1 : 0;
    const int   rB = (wv < 7) ? r0 + 8 : 63;

    const float* wbase = Wt + (size_t)k * FAN_IN * 9;

    float acc[8];
    #pragma unroll
    for (int s = 0; s < 8; ++s) acc[s] = 0.0f;

    // one DMA issue stages the whole 8 KB map: 512 lanes x 16 B.
    // LDS base wave-uniform (wv*1024 B); global src per-lane (tid*16 B).
#define STAGE(buf, p)                                                          \
    __builtin_amdgcn_global_load_lds(                                          \
        (const __attribute__((address_space(1))) unsigned*)                    \
            ((const char*)maps16 + (size_t)(p) * 8192 + tid * 16),             \
        (__attribute__((address_space(3))) unsigned*)                          \
            ((char*)&sbuf[buf][0] + wv * 1024),                                \
        16, 0, 0);

    STAGE(0, pidx[0]);
    __syncthreads();                 // vmcnt(0) drain + handoff: buf0 ready

    #pragma unroll 2
    for (int ch = 0; ch < FAN_IN; ++ch) {
        if (ch + 1 < FAN_IN) STAGE((ch + 1) & 1, pidx[ch + 1]);

        const unsigned short* sb = sbuf[ch & 1];
        const float* w = wbase + ch * 9;
        const float wl0 = w[0], wc0 = w[1], wr0 = w[2];
        const float wl1 = w[3], wc1 = w[4], wr1 = w[5];
        const float wl2 = w[6], wc2 = w[7], wr2 = w[8];

        float v[10], l[10], r[10];
        v[0] = bf2f(sb[rT * NSP + lane]) * mT;
        #pragma unroll
        for (int j = 1; j <= 8; ++j) v[j] = bf2f(sb[(r0 - 1 + j) * NSP + lane]);
        v[9] = bf2f(sb[rB * NSP + lane]) * mB;
        #pragma unroll
        for (int j = 0; j < 10; ++j) { l[j] = dpp_wshr1(v[j]); r[j] = dpp_wshl1(v[j]); }

        #pragma unroll
        for (int s = 0; s < 8; ++s) {
            float a = acc[s];
            a = fmaf(wl0, l[s],     fmaf(wc0, v[s],     fmaf(wr0, r[s],     a)));
            a = fmaf(wl1, l[s + 1], fmaf(wc1, v[s + 1], fmaf(wr1, r[s + 1], a)));
            a = fmaf(wl2, l[s + 2], fmaf(wc2, v[s + 2], fmaf(wr2, r[s + 2], a)));
            acc[s] = a;
        }

        if (ch + 1 < FAN_IN) __syncthreads();
    }
#undef STAGE

    const float bk = bias[k];
    #pragma unroll
    for (int s = 0; s < 8; ++s)
        out[obase + (size_t)(r0 + s) * NSP + lane] = tanh_fast(acc[s] + bk);
}

// ---- f32 fallback (R9 verbatim) in case ws is too small ----
__device__ __forceinline__ void gload_lds16f(const float* g, float* l) {
    __builtin_amdgcn_global_load_lds(
        (const __attribute__((address_space(1))) unsigned*)g,
        (__attribute__((address_space(3)))       unsigned*)l,
        16, 0, 0);
}

__global__ __launch_bounds__(512, 8) void decoder_f32(
    const float* __restrict__ prev_outputs,
    const void*  __restrict__ prev_is_active,
    const int*   __restrict__ parent_indices,
    const float* __restrict__ Wt,
    const float* __restrict__ bias,
    float*       __restrict__ out)
{
    __shared__ float sbuf[2][MAPB];

    const int k    = blockIdx.x;
    const int tid  = threadIdx.x;
    const int lane = tid & 63;
    const int wv   = tid >> 6;
    const int r0   = wv * 8;

    bool bytemode = false;
    {
        const unsigned* sv = (const unsigned*)prev_is_active;
        #pragma unroll
        for (int i = 0; i < 16; ++i)
            if (sv[i] > 1u) bytemode = true;
    }

    const int* pidx = parent_indices + k * FAN_IN;
    int cnt = 0;
    #pragma unroll
    for (int i = 0; i < FAN_IN; ++i) {
        int p = pidx[i];
        int f;
        if (bytemode) f = (((const unsigned char*)prev_is_active)[p] != 0);
        else          f = (((const int*)prev_is_active)[p] != 0);
        cnt += f;
    }
    const bool active = (cnt >= THRESH);

    const size_t obase = (size_t)k * MAPB;
    if (tid == 0)
        out[(size_t)KN * MAPB + k] = active ? 1.0f : 0.0f;

    if (!active) {
        float4 z = make_float4(0.f, 0.f, 0.f, 0.f);
        float4* o4 = (float4*)(out + obase);
        o4[tid]       = z;
        o4[tid + 512] = z;
        return;
    }

    const float mT = (wv > 0) ? 1.0f : 0.0f;
    const float mB = (wv < 7) ? 1.0f : 0.0f;
    const int   rT = (wv > 0) ? r0 - 1 : 0;
    const int   rB = (wv < 7) ? r0 + 8 : 63;

    const float* wbase = Wt + (size_t)k * FAN_IN * 9;

    float acc[8];
    #pragma unroll
    for (int s = 0; s < 8; ++s) acc[s] = 0.0f;

#define STAGE(buf, p)                                                         \
    {                                                                         \
        const float* g = prev_outputs + (size_t)(p) * MAPB;                   \
        gload_lds16f(g + tid * 4,        &sbuf[buf][wv * 256]);               \
        gload_lds16f(g + 2048 + tid * 4, &sbuf[buf][2048 + wv * 256]);        \
    }

    STAGE(0, pidx[0]);
    __syncthreads();

    #pragma unroll 2
    for (int ch = 0; ch < FAN_IN; ++ch) {
        if (ch + 1 < FAN_IN) STAGE((ch + 1) & 1, pidx[ch + 1]);

        const float* sb = sbuf[ch & 1];
        const float* w  = wbase + ch * 9;
        const float wl0 = w[0], wc0 = w[1], wr0 = w[2];
        const float wl1 = w[3], wc1 = w[4], wr1 = w[5];
        const float wl2 = w[6], wc2 = w[7], wr2 = w[8];

        float v[10], l[10], r[10];
        v[0] = sb[rT * NSP + lane] * mT;
        #pragma unroll
        for (int j = 1; j <= 8; ++j) v[j] = sb[(r0 - 1 + j) * NSP + lane];
        v[9] = sb[rB * NSP + lane] * mB;
        #pragma unroll
        for (int j = 0; j < 10; ++j) { l[j] = dpp_wshr1(v[j]); r[j] = dpp_wshl1(v[j]); }

        #pragma unroll
        for (int s = 0; s < 8; ++s) {
            float a = acc[s];
            a = fmaf(wl0, l[s],     fmaf(wc0, v[s],     fmaf(wr0, r[s],     a)));
            a = fmaf(wl1, l[s + 1], fmaf(wc1, v[s + 1], fmaf(wr1, r[s + 1], a)));
            a = fmaf(wl2, l[s + 2], fmaf(wc2, v[s + 2], fmaf(wr2, r[s + 2], a)));
            acc[s] = a;
        }

        if (ch + 1 < FAN_IN) __syncthreads();
    }
#undef STAGE

    const float bk = bias[k];
    #pragma unroll
    for (int s = 0; s < 8; ++s)
        out[obase + (size_t)(r0 + s) * NSP + lane] = tanh_fast(acc[s] + bk);
}

extern "C" void kernel_launch(void* const* d_in, const int* in_sizes, int n_in,
                              void* d_out, int out_size, void* d_ws, size_t ws_size,
                              hipStream_t stream) {
    const float* prev_outputs   = (const float*)d_in[0];
    const void*  prev_is_active = d_in[1];
    const int*   parent_indices = (const int*)d_in[2];
    const float* Wt             = (const float*)d_in[3];
    const float* bias           = (const float*)d_in[4];
    float*       out            = (float*)d_out;

    const size_t need = (size_t)KN * MAPB * sizeof(unsigned short);  // 8 MB
    if (ws_size >= need) {
        unsigned short* maps16 = (unsigned short*)d_ws;
        compress_kernel<<<dim3(KN * MAPB / (256 * 4)), dim3(256), 0, stream>>>(
            prev_outputs, maps16);
        decoder_bf16<<<dim3(KN), dim3(512), 0, stream>>>(
            maps16, prev_is_active, parent_indices, Wt, bias, out);
    } else {
        decoder_f32<<<dim3(KN), dim3(512), 0, stream>>>(
            prev_outputs, prev_is_active, parent_indices, Wt, bias, out);
    }
}